// Round 7
// baseline (215.073 us; speedup 1.0000x reference)
//
#include <hip/hip_runtime.h>

#define N_NODES 4096
#define FIN     512
#define FOUT    256

typedef __attribute__((ext_vector_type(8))) short bf16x8s;
typedef __attribute__((ext_vector_type(4))) float f32x4;
typedef __attribute__((ext_vector_type(8))) unsigned short u16x8;
typedef unsigned short u16;
typedef unsigned int   u32;

__device__ inline u16 f2b(float f) {
    union { float f; unsigned int u; } v; v.f = f;
    unsigned int r = v.u + 0x7fffu + ((v.u >> 16) & 1u);   // RTNE
    return (u16)(r >> 16);
}

// ---------------------------------------------------------------------------
// prep: [0,1024)    h fp32 -> hb bf16
//       [1024,1088) W_b -> WTb bf16 transposed [n][k]
//       [1088]      zero s1/s2
// ---------------------------------------------------------------------------
__global__ __launch_bounds__(256) void prep_kernel(
    const float* __restrict__ h, const float* __restrict__ Wn,
    const float* __restrict__ Wd,
    u16* __restrict__ hb, u16* __restrict__ WTb, float* __restrict__ s12)
{
    __shared__ u16 tl[64 * 72];
    const int t = threadIdx.x;
    const int bid = blockIdx.x;

    if (bid < 1024) {                       // h convert
        int idx = (bid * 256 + t) * 8;
        float4 f0 = *(const float4*)&h[idx];
        float4 f1 = *(const float4*)&h[idx + 4];
        u16x8 o;
        o[0]=f2b(f0.x); o[1]=f2b(f0.y); o[2]=f2b(f0.z); o[3]=f2b(f0.w);
        o[4]=f2b(f1.x); o[5]=f2b(f1.y); o[6]=f2b(f1.z); o[7]=f2b(f1.w);
        *(u16x8*)&hb[idx] = o;
    } else if (bid < 1088) {                // W transpose+convert, 64x64 tiles
        int id = bid - 1024;
        int kx = id & 7, ny = (id >> 3) & 3, b = id >> 5;
        const float* W = b ? Wd : Wn;
        int k0 = kx * 64, n0 = ny * 64;
        int kr = t >> 2, nc0 = (t & 3) * 16;
        const float* src = W + (size_t)(k0 + kr) * FOUT + n0 + nc0;
        #pragma unroll
        for (int jv = 0; jv < 4; ++jv) {
            float4 f = *(const float4*)(src + jv * 4);
            tl[(nc0 + jv * 4 + 0) * 72 + kr] = f2b(f.x);
            tl[(nc0 + jv * 4 + 1) * 72 + kr] = f2b(f.y);
            tl[(nc0 + jv * 4 + 2) * 72 + kr] = f2b(f.z);
            tl[(nc0 + jv * 4 + 3) * 72 + kr] = f2b(f.w);
        }
        __syncthreads();
        int n = t >> 2, kc0 = (t & 3) * 16;
        u16* dst = WTb + ((size_t)b << 17) + (size_t)(n0 + n) * FIN + k0 + kc0;
        *(uint4*)dst       = *(uint4*)&tl[n * 72 + kc0];
        *(uint4*)(dst + 8) = *(uint4*)&tl[n * 72 + kc0 + 8];
    } else {                                // zero s1,s2 (16384 floats)
        float4 z = {0.f, 0.f, 0.f, 0.f};
        float4* p4 = (float4*)s12;
        #pragma unroll
        for (int k = 0; k < 16; ++k) p4[k * 256 + t] = z;
    }
}

// ---------------------------------------------------------------------------
// wh_gemm: WhT[b][n][i] = (hb @ W_b)[i][n]; epilogue accumulates s1/s2.
// grid (64, 4, 2).
// ---------------------------------------------------------------------------
__global__ __launch_bounds__(256) void wh_gemm_kernel(
    const u16* __restrict__ hb, const u16* __restrict__ WTb,
    const float* __restrict__ a1n, const float* __restrict__ a2n,
    const float* __restrict__ a1d, const float* __restrict__ a2d,
    u16* __restrict__ WhT, float* __restrict__ s1, float* __restrict__ s2)
{
    __shared__ u16 smem[8192];
    u16* a_lds = smem;
    u16* b_lds = smem + 4096;

    const int t = threadIdx.x, lane = t & 63, w = t >> 6;
    const int q = lane >> 4, ln = lane & 15;
    const int i0 = blockIdx.x * 64, n0 = blockIdx.y * 64, b = blockIdx.z;
    const u16* wt = WTb + ((size_t)b << 17);

    f32x4 acc[4];
    #pragma unroll
    for (int i = 0; i < 4; ++i) acc[i] = (f32x4){0.f, 0.f, 0.f, 0.f};

    for (int kt = 0; kt < 8; ++kt) {
        const int k0 = kt * 64;
        __syncthreads();
        #pragma unroll
        for (int it = 0; it < 2; ++it) {
            int chunk = it * 256 + t;
            int r = chunk >> 3, kc = chunk & 7;
            const u16* g = hb + (size_t)(i0 + r) * FIN + k0 + ((kc ^ (r & 7)) * 8);
            u16* l = a_lds + (it * 256 + w * 64) * 8;
            __builtin_amdgcn_global_load_lds(
                (const __attribute__((address_space(1))) void*)g,
                (__attribute__((address_space(3))) void*)l, 16, 0, 0);
        }
        #pragma unroll
        for (int it = 0; it < 2; ++it) {
            int chunk = it * 256 + t;
            int n = chunk >> 3, kc = chunk & 7;
            const u16* g = wt + (size_t)(n0 + n) * FIN + k0 + ((kc ^ (n & 7)) * 8);
            u16* l = b_lds + (it * 256 + w * 64) * 8;
            __builtin_amdgcn_global_load_lds(
                (const __attribute__((address_space(1))) void*)g,
                (__attribute__((address_space(3))) void*)l, 16, 0, 0);
        }
        __syncthreads();
        #pragma unroll
        for (int ks = 0; ks < 2; ++ks) {
            int sw = ((ks * 4 + q) ^ (ln & 7)) * 8;
            bf16x8s af = *(const bf16x8s*)&a_lds[(w * 16 + ln) * 64 + sw];
            #pragma unroll
            for (int nt = 0; nt < 4; ++nt) {
                bf16x8s bfv = *(const bf16x8s*)&b_lds[(nt * 16 + ln) * 64 + sw];
                acc[nt] = __builtin_amdgcn_mfma_f32_16x16x32_bf16(af, bfv, acc[nt], 0, 0, 0);
            }
        }
    }

    {
        const float* a1 = b ? a1d : a1n;
        const float* a2 = b ? a2d : a2n;
        float s1p[4] = {0.f, 0.f, 0.f, 0.f};
        float s2p[4] = {0.f, 0.f, 0.f, 0.f};
        #pragma unroll
        for (int nt = 0; nt < 4; ++nt) {
            float va1 = a1[n0 + nt * 16 + ln];
            float va2 = a2[n0 + nt * 16 + ln];
            #pragma unroll
            for (int r = 0; r < 4; ++r) {
                s1p[r] += acc[nt][r] * va1;
                s2p[r] += acc[nt][r] * va2;
            }
        }
        #pragma unroll
        for (int r = 0; r < 4; ++r) {
            #pragma unroll
            for (int off = 8; off >= 1; off >>= 1) {
                s1p[r] += __shfl_xor(s1p[r], off);
                s2p[r] += __shfl_xor(s2p[r], off);
            }
            if (ln == 0) {
                int row = i0 + w * 16 + q * 4 + r;
                atomicAdd(&s1[b * N_NODES + row], s1p[r]);
                atomicAdd(&s2[b * N_NODES + row], s2p[r]);
            }
        }
    }

    __syncthreads();
    #pragma unroll
    for (int nt = 0; nt < 4; ++nt)
        #pragma unroll
        for (int r = 0; r < 4; ++r)
            smem[(nt * 16 + ln) * 72 + (w * 16 + q * 4 + r)] = f2b(acc[nt][r]);
    __syncthreads();
    {
        const int nl = t >> 2, is = (t & 3) * 16;
        u16* dst = WhT + ((size_t)b << 20) + (size_t)(n0 + nl) * N_NODES + i0 + is;
        *(uint4*)dst       = *(uint4*)&smem[nl * 72 + is];
        *(uint4*)(dst + 8) = *(uint4*)&smem[nl * 72 + is + 8];
    }
}

// ---------------------------------------------------------------------------
// attn: 64 rows x (4096/nsplit) j per block; adj direct; prefetch issued
// AFTER the pre-MFMA barrier so it rides out the MFMA phase; den in regs.
// LDS exactly 40960 B -> 4 blocks/CU. grid (64, nsplit, 2).
// ---------------------------------------------------------------------------
__global__ __launch_bounds__(256) void attn_kernel(
    const int* __restrict__ adj_n, const int* __restrict__ adj_d,
    const u16* __restrict__ WhT,
    const float* __restrict__ s1, const float* __restrict__ s2,
    float* __restrict__ num_ws, float* __restrict__ den_ws, int nsplit)
{
    __shared__ u16 smem_all[20480];     // wht: [0,16384) u16 (32 KB), p: [16384,20480) (8 KB)
    u16* wht_lds = smem_all;
    u16* p_lds   = smem_all + 16384;

    const int t = threadIdx.x, lane = t & 63, w = t >> 6;
    const int q = lane >> 4, ln = lane & 15;
    const int b = blockIdx.z, split = blockIdx.y;
    const int i0 = blockIdx.x * 64;
    const int jcount = N_NODES / nsplit;
    const int ntiles = jcount / 64;

    const int* adjb = b ? adj_d : adj_n;
    const u16* whtB = WhT + ((size_t)b << 20);
    const float* s1b = s1 + b * N_NODES;
    const float* s2b = s2 + b * N_NODES;

    const int pr = t >> 3;              // P row 0..31 (also handles pr+32)
    const int cw = t & 7;               // P k-chunk 0..7
    const int pc = cw * 8;
    const float s1v0 = s1b[i0 + pr];
    const float s1v1 = s1b[i0 + pr + 32];
    const size_t arow0 = (size_t)(i0 + pr) * N_NODES + pc;
    const size_t arow1 = arow0 + (size_t)32 * N_NODES;

    float den0 = 0.f, den1 = 0.f;       // per-thread den accumulators (across tiles)

    f32x4 acc[4][4];
    #pragma unroll
    for (int mt = 0; mt < 4; ++mt)
        #pragma unroll
        for (int nt = 0; nt < 4; ++nt) acc[mt][nt] = (f32x4){0.f, 0.f, 0.f, 0.f};

    const int jbase = split * jcount;
    int4 a00_pf = *(const int4*)&adjb[arow0 + jbase];
    int4 a01_pf = *(const int4*)&adjb[arow0 + jbase + 4];
    int4 a10_pf = *(const int4*)&adjb[arow1 + jbase];
    int4 a11_pf = *(const int4*)&adjb[arow1 + jbase + 4];
    float4 sv0_pf = *(const float4*)&s2b[jbase + pc];
    float4 sv1_pf = *(const float4*)&s2b[jbase + pc + 4];

    for (int jt = 0; jt < ntiles; ++jt) {
        const int j0 = jbase + jt * 64;
        __syncthreads();                   // barrier1: wht_lds free; drains last prefetch
        #pragma unroll
        for (int it = 0; it < 8; ++it) {   // stage 256n x 64j WhT tile
            int chunk = it * 256 + t;
            int n = chunk >> 3, kc = chunk & 7;
            const u16* g = whtB + (size_t)n * N_NODES + j0 + ((kc ^ (n & 7)) * 8);
            u16* l = wht_lds + (it * 256 + w * 64) * 8;
            __builtin_amdgcn_global_load_lds(
                (const __attribute__((address_space(1))) void*)g,
                (__attribute__((address_space(3))) void*)l, 16, 0, 0);
        }
        int v0[8] = {a00_pf.x, a00_pf.y, a00_pf.z, a00_pf.w, a01_pf.x, a01_pf.y, a01_pf.z, a01_pf.w};
        int v1[8] = {a10_pf.x, a10_pf.y, a10_pf.z, a10_pf.w, a11_pf.x, a11_pf.y, a11_pf.z, a11_pf.w};
        float svf[8] = {sv0_pf.x, sv0_pf.y, sv0_pf.z, sv0_pf.w, sv1_pf.x, sv1_pf.y, sv1_pf.z, sv1_pf.w};
        u16x8 pk0, pk1;
        #pragma unroll
        for (int jj = 0; jj < 8; ++jj) {
            float sv = svf[jj];
            float x0 = s1v0 + sv, x1 = s1v1 + sv;
            float p0 = (v0[jj] > 0) ? __expf(fmaxf(x0, 0.2f * x0)) : 0.f;
            float p1 = (v1[jj] > 0) ? __expf(fmaxf(x1, 0.2f * x1)) : 0.f;
            den0 += p0; den1 += p1;
            pk0[jj] = f2b(p0); pk1[jj] = f2b(p1);
        }
        int swp = ((cw ^ (pr & 7)) * 8);
        *(u16x8*)&p_lds[pr * 64 + swp] = pk0;
        *(u16x8*)&p_lds[(pr + 32) * 64 + swp] = pk1;
        __syncthreads();                   // barrier2: drains glds; P visible
        if (jt + 1 < ntiles) {             // prefetch next tile; in flight across MFMA phase
            const int jn = j0 + 64;
            a00_pf = *(const int4*)&adjb[arow0 + jn];
            a01_pf = *(const int4*)&adjb[arow0 + jn + 4];
            a10_pf = *(const int4*)&adjb[arow1 + jn];
            a11_pf = *(const int4*)&adjb[arow1 + jn + 4];
            sv0_pf = *(const float4*)&s2b[jn + pc];
            sv1_pf = *(const float4*)&s2b[jn + pc + 4];
        }
        #pragma unroll
        for (int ks = 0; ks < 2; ++ks) {
            int sw = ((ks * 4 + q) ^ (ln & 7)) * 8;
            bf16x8s af[4];
            #pragma unroll
            for (int mt = 0; mt < 4; ++mt)
                af[mt] = *(const bf16x8s*)&p_lds[(mt * 16 + ln) * 64 + sw];
            #pragma unroll
            for (int nt = 0; nt < 4; ++nt) {
                bf16x8s bfv = *(const bf16x8s*)&wht_lds[(w * 64 + nt * 16 + ln) * 64 + sw];
                #pragma unroll
                for (int mt = 0; mt < 4; ++mt)
                    acc[mt][nt] = __builtin_amdgcn_mfma_f32_16x16x32_bf16(af[mt], bfv, acc[mt][nt], 0, 0, 0);
            }
        }
    }
    // den: reduce across the 8 cw lanes once
    den0 += __shfl_down(den0, 4, 8); den1 += __shfl_down(den1, 4, 8);
    den0 += __shfl_down(den0, 2, 8); den1 += __shfl_down(den1, 2, 8);
    den0 += __shfl_down(den0, 1, 8); den1 += __shfl_down(den1, 1, 8);
    const size_t pbase = (size_t)(b * nsplit + split) * N_NODES;
    if ((t & 7) == 0) {
        den_ws[pbase + i0 + pr] = den0;
        den_ws[pbase + i0 + pr + 32] = den1;
    }
    #pragma unroll
    for (int mt = 0; mt < 4; ++mt)
        #pragma unroll
        for (int r = 0; r < 4; ++r) {
            int row = mt * 16 + q * 4 + r;
            #pragma unroll
            for (int nt = 0; nt < 4; ++nt)
                num_ws[(pbase + i0 + row) * FOUT + w * 64 + nt * 16 + ln] = acc[mt][nt][r];
        }
}

// ---------------------------------------------------------------------------
// reduce: sum splits, elu(num/den), merge branches.
// ---------------------------------------------------------------------------
__global__ __launch_bounds__(256) void reduce_kernel(
    const float* __restrict__ num_ws, const float* __restrict__ den_ws,
    float* __restrict__ out, int nsplit)
{
    int gid = blockIdx.x * 256 + threadIdx.x;
    int i = gid >> 6;
    int f4 = (gid & 63) * 4;
    float4 o = {0.f, 0.f, 0.f, 0.f};
    #pragma unroll
    for (int b = 0; b < 2; ++b) {
        float4 num = {0.f, 0.f, 0.f, 0.f};
        float den = 0.f;
        for (int s = 0; s < nsplit; ++s) {
            const float4 v = *(const float4*)&num_ws[((size_t)(b * nsplit + s) * N_NODES + i) * FOUT + f4];
            num.x += v.x; num.y += v.y; num.z += v.z; num.w += v.w;
            den += den_ws[(size_t)(b * nsplit + s) * N_NODES + i];
        }
        float inv = 1.0f / den;
        float e0 = num.x * inv, e1 = num.y * inv, e2 = num.z * inv, e3 = num.w * inv;
        o.x += (e0 > 0.f) ? e0 : expm1f(e0);
        o.y += (e1 > 0.f) ? e1 : expm1f(e1);
        o.z += (e2 > 0.f) ? e2 : expm1f(e2);
        o.w += (e3 > 0.f) ? e3 : expm1f(e3);
    }
    *(float4*)&out[(size_t)i * FOUT + f4] = o;
}

extern "C" void kernel_launch(void* const* d_in, const int* in_sizes, int n_in,
                              void* d_out, int out_size, void* d_ws, size_t ws_size,
                              hipStream_t stream) {
    const float* h    = (const float*)d_in[0];
    const int*   adjn = (const int*)d_in[1];
    const int*   adjd = (const int*)d_in[2];
    const float* Wn   = (const float*)d_in[4];
    const float* a1n  = (const float*)d_in[5];
    const float* a2n  = (const float*)d_in[6];
    const float* Wd   = (const float*)d_in[7];
    const float* a1d  = (const float*)d_in[8];
    const float* a2d  = (const float*)d_in[9];

    char* ws = (char*)d_ws;
    // [0,4M): WhT   [8M,8M+~300K): s1,s2,den
    // [8.65M,12.65M): hb  [12.65M,13.15M): WTb  (dead after wh_gemm)
    // [8.65M, 8.65M + nsplit*8.39M): num (overlays hb/WTb)
    u16*  WhT  = (u16*)ws;
    float* s1  = (float*)(ws + ((size_t)8 << 20));
    float* s2  = s1 + 2 * N_NODES;
    float* den = s2 + 2 * N_NODES;                    // up to 2*8*4096 f32 = 256 KB
    size_t num_off = ((size_t)8 << 20) + ((size_t)400 << 10);
    u16*  hb   = (u16*)(ws + num_off);
    u16*  WTb  = (u16*)(ws + num_off + ((size_t)4 << 20));
    float* num = (float*)(ws + num_off);

    const size_t per_split = (size_t)2 * N_NODES * FOUT * sizeof(float);  // 8.39 MB
    int nsplit = (ws_size >= num_off + 8 * per_split) ? 8 : 4;

    prep_kernel<<<1089, 256, 0, stream>>>(h, Wn, Wd, hb, WTb, s1);
    wh_gemm_kernel<<<dim3(64, 4, 2), 256, 0, stream>>>(hb, WTb, a1n, a2n, a1d, a2d, WhT, s1, s2);
    attn_kernel<<<dim3(64, nsplit, 2), 256, 0, stream>>>(adjn, adjd, WhT, s1, s2, num, den, nsplit);
    reduce_kernel<<<1024, 256, 0, stream>>>(num, den, (float*)d_out, nsplit);
}